// Round 5
// baseline (348.042 us; speedup 1.0000x reference)
//
#include <hip/hip_runtime.h>
#include <hip/hip_cooperative_groups.h>

namespace cg = cooperative_groups;

// RepulsionLoss: points [B=4, N=8192, 3] fp32 -> scalar.
// Round 13: ONE cooperative dispatch (build + query fused) + 2 waves/SIMD.
//   R12 post-mortem: query 48us is LDS-latency serialization at 1 wave/SIMD
//   (Occ 4.76%): both lanes walked all 98 ring-2 rows; ds_read ~120cy each,
//   dependent insert defeats pipelining. ALSO: total - query = ~58us constant
//   across R8-R12 = 4 build dispatches + memset + gaps.
//   Fixes: (a) 512-thread blocks, 4 lanes/point -> per-lane chain halves and
//   8 waves/CU = 2/SIMD hide each other's LDS stalls. (b) fuse the 5
//   dispatches into one hipLaunchCooperativeKernel with grid.sync() phases
//   (256 blocks x 512 thr, 77KB LDS = exactly 1 block/CU co-resident).
//   Scan phase = 4 single-wave shfl prefix scans (no __syncthreads).

#define B_    4
#define N_    8192
#define KNN_  8
#define G_    12
#define C_    (G_ * G_ * G_)   // 1728
#define CS_   (C_ + 1)
#define PLANE_ (G_ * G_)       // 144
#define SLAB_CAP 4608          // float4 slots: 6 planes avg 4096, 11-sigma cap
#define CS_CAP   (6 * PLANE_ + 1)  // 865
#define THREADS_ 512
#define BLOCKS_  256           // 128 points/block; 1 block/CU (cooperative)

constexpr float GF_     = (float)G_;
constexpr float CELL_   = 1.0f / GF_;
constexpr float RADIUS_ = 0.07f;
constexpr float INV_H2_ = 1.0f / (0.03f * 0.03f);
constexpr float SCALE_  = 0.1f / (float)(B_ * N_ * KNN_);   // ALPHA / (B*N*K)

__device__ __forceinline__ int cell_coord(float x) {
    int c = (int)(x * GF_);
    return min(max(c, 0), G_ - 1);
}

__device__ __forceinline__ void insert8(float (&t)[KNN_], float v) {
#pragma unroll
    for (int k = 0; k < KNN_; k++) {
        const float lo = fminf(t[k], v);
        v = fmaxf(t[k], v);
        t[k] = lo;
    }
}

// One bitonic merge stage across lane pairs (xor dist): both lanes end with
// the sorted min-8 of the union of their two sorted lists. Valid for disjoint
// candidate multisets.
__device__ __forceinline__ void merge_pair(float (&t)[KNN_], const int dist) {
    float u[KNN_];
#pragma unroll
    for (int i2 = 0; i2 < KNN_; i2++)
        u[i2] = fminf(t[i2], __shfl_xor(t[KNN_ - 1 - i2], dist));
#pragma unroll
    for (int d = 4; d >= 1; d >>= 1) {
#pragma unroll
        for (int i2 = 0; i2 < KNN_; i2++) {
            if ((i2 & d) == 0) {
                const float a = u[i2], e = u[i2 + d];
                u[i2] = fminf(a, e); u[i2 + d] = fmaxf(a, e);
            }
        }
    }
#pragma unroll
    for (int i2 = 0; i2 < KNN_; i2++) t[i2] = u[i2];
}

// Span scan from the LDS slab (slab-local indices), 4-way lane split.
__device__ __forceinline__ void scan_lds(const float4 (&sl)[SLAB_CAP],
                                         int j0, int j1, int l,
                                         float px, float py, float pz,
                                         float (&t)[KNN_]) {
    for (int j = j0 + l; j < j1; j += 4) {
        const float4 Q = sl[j];
        const float dx = px - Q.x, dy = py - Q.y, dz = pz - Q.z;
        const float d2 = dx * dx + dy * dy + dz * dz;
        if (d2 < t[KNN_ - 1]) insert8(t, d2);
    }
}

// Span scan from global memory (ring >=3 only, essentially never).
__device__ __forceinline__ void scan_glb(const float4* __restrict__ sp,
                                         int j0, int j1, int l,
                                         float px, float py, float pz,
                                         float (&t)[KNN_]) {
    for (int j = j0 + l; j < j1; j += 4) {
        const float4 Q = sp[j];
        const float dx = px - Q.x, dy = py - Q.y, dz = pz - Q.z;
        const float d2 = dx * dx + dy * dy + dz * dz;
        if (d2 < t[KNN_ - 1]) insert8(t, d2);
    }
}

__global__ __launch_bounds__(THREADS_) void fused_kernel(
    const float* __restrict__ pts,
    int* __restrict__ counts,
    int* __restrict__ cellStart,
    int* __restrict__ cursor,
    float4* __restrict__ sorted4,
    float* __restrict__ out)
{
    __shared__ float4 slab[SLAB_CAP];
    __shared__ int    scs[CS_CAP];
    __shared__ float  bsum[8];

    cg::grid_group grid = cg::this_grid();
    const int tid = threadIdx.x;
    const int gid = blockIdx.x * THREADS_ + tid;

    // ---- phase 0: zero counts, zero out (out re-poisoned each replay) ----
    if (gid < B_ * C_) counts[gid] = 0;
    if (gid == 0) out[0] = 0.0f;
    __threadfence();
    grid.sync();

    // ---- phase 1: count ----
    if (gid < B_ * N_) {
        const int b = gid >> 13;
        const float x = pts[gid * 3 + 0], y = pts[gid * 3 + 1], z = pts[gid * 3 + 2];
        const int id = (cell_coord(z) * G_ + cell_coord(y)) * G_ + cell_coord(x);
        atomicAdd(&counts[b * C_ + id], 1);
    }
    __threadfence();
    grid.sync();

    // ---- phase 2: scan (blocks 0..3, wave 0 each; 27 cells/lane, shfl scan) ----
    if (blockIdx.x < B_ && tid < 64) {
        const int b = blockIdx.x, lane = tid;
        const int* cnt = counts + b * C_;
        int vals[27], tot = 0;
        const int c0 = lane * 27;                   // 64*27 = 1728 exactly
#pragma unroll
        for (int k = 0; k < 27; k++) { const int v = cnt[c0 + k]; vals[k] = v; tot += v; }
        int incl = tot;
#pragma unroll
        for (int off = 1; off < 64; off <<= 1) {
            const int v = __shfl_up(incl, off, 64);
            if (lane >= off) incl += v;
        }
        int run = incl - tot;                       // exclusive base
#pragma unroll
        for (int k = 0; k < 27; k++) {
            cellStart[b * CS_ + c0 + k] = run;
            cursor[b * C_ + c0 + k]     = run;
            run += vals[k];
        }
        if (lane == 63) cellStart[b * CS_ + C_] = N_;
    }
    __threadfence();
    grid.sync();

    // ---- phase 3: scatter ----
    if (gid < B_ * N_) {
        const int b = gid >> 13;
        const float x = pts[gid * 3 + 0], y = pts[gid * 3 + 1], z = pts[gid * 3 + 2];
        const int id = (cell_coord(z) * G_ + cell_coord(y)) * G_ + cell_coord(x);
        const int pos = atomicAdd(&cursor[b * C_ + id], 1);
        sorted4[(size_t)b * N_ + pos] = make_float4(x, y, z, 0.0f);
    }
    __threadfence();
    grid.sync();

    // ---- phase 4: query (128 points/block, 4 lanes/point) ----
    const int b    = blockIdx.x >> 6;                  // 64 blocks/batch
    const int base = (blockIdx.x & 63) << 7;           // first point of block
    const int i    = base + (tid >> 2);                // this thread's point
    const int l    = tid & 3;                          // lane within point

    const int*    csg = cellStart + b * CS_;
    const float4* sp  = sorted4 + (size_t)b * N_;

    // Slab: block's points are cell-sorted; all ring<=2 reach lies in
    // z-planes [zf-2, zl+2] (<=6 planes; SLAB_CAP is ~11 sigma).
    const int zf  = cell_coord(sp[base].z);
    const int zl  = cell_coord(sp[base + 127].z);
    const int zlo = max(zf - 2, 0), zhi = min(zl + 2, G_ - 1);
    const int cs0 = zlo * PLANE_;
    const int cs1 = (zhi + 1) * PLANE_;                // <= C_
    const int start = csg[cs0];
    const int cnt   = csg[cs1] - start;
    const int csn   = cs1 - cs0 + 1;
    for (int k = tid; k < csn; k += THREADS_) scs[k]  = csg[cs0 + k];
    for (int k = tid; k < cnt; k += THREADS_) slab[k] = sp[start + k];
    __syncthreads();

    const float4 P = slab[i - start];
    const float px = P.x, py = P.y, pz = P.z;
    const int cx = cell_coord(px), cy = cell_coord(py), cz = cell_coord(pz);

    // Rings 0+1: 9 raster-contiguous x-rows, bounds from LDS cellStart slice.
    const int xa = max(cx - 1, 0), xb = min(cx + 1, G_ - 1);
    int j0[9], j1[9];
#pragma unroll
    for (int n = 0; n < 9; n++) {
        const int dz = n / 3 - 1, dy = n % 3 - 1;
        const int z = cz + dz, y = cy + dy;
        if ((unsigned)z < G_ && (unsigned)y < G_) {
            const int rb = (z * G_ + y) * G_ - cs0;
            j0[n] = scs[rb + xa] - start;
            j1[n] = scs[rb + xb + 1] - start;
        } else { j0[n] = 0; j1[n] = 0; }
    }

    float t[KNN_];
#pragma unroll
    for (int k = 0; k < KNN_; k++) t[k] = 1e30f;

#pragma unroll
    for (int n = 0; n < 9; n++)
        scan_lds(slab, j0[n], j1[n], l, px, py, pz, t);

    // True merged 8th-NN bound over the 4 lanes via temp copy.
    float m;
    {
        float tmp[KNN_];
#pragma unroll
        for (int k = 0; k < KNN_; k++) tmp[k] = t[k];
        merge_pair(tmp, 1); merge_pair(tmp, 2);
        m = tmp[KNN_ - 1];
    }

    // Exact fallback: ring r while ((r-1)*g)^2 < m. r==2 reads LDS (staged);
    // r>=3 (8th-NN > 2 cells: essentially never) reads global.
    for (int r = 2; r < G_; r++) {
        const float dmin = (float)(r - 1) * CELL_;
        if (dmin * dmin >= m) break;
        if (r == 2) {
            for (int dz = -2; dz <= 2; ++dz) {
                const int z = cz + dz; if ((unsigned)z >= G_) continue;
                const bool zface = (dz == -2) | (dz == 2);
                for (int dy = -2; dy <= 2; ++dy) {
                    const int y = cy + dy; if ((unsigned)y >= G_) continue;
                    const int rb = (z * G_ + y) * G_ - cs0;
                    if (zface | (dy == -2) | (dy == 2)) {
                        const int x0 = max(cx - 2, 0), x1 = min(cx + 2, G_ - 1);
                        scan_lds(slab, scs[rb + x0] - start, scs[rb + x1 + 1] - start,
                                 l, px, py, pz, t);
                    } else {
                        const int xm = cx - 2, xp = cx + 2;
                        if (xm >= 0)
                            scan_lds(slab, scs[rb + xm] - start, scs[rb + xm + 1] - start,
                                     l, px, py, pz, t);
                        if (xp < G_)
                            scan_lds(slab, scs[rb + xp] - start, scs[rb + xp + 1] - start,
                                     l, px, py, pz, t);
                    }
                }
            }
        } else {
            for (int dz = -r; dz <= r; ++dz) {
                const int z = cz + dz; if ((unsigned)z >= G_) continue;
                const bool zface = (dz == -r) | (dz == r);
                for (int dy = -r; dy <= r; ++dy) {
                    const int y = cy + dy; if ((unsigned)y >= G_) continue;
                    const int rb = (z * G_ + y) * G_;
                    if (zface | (dy == -r) | (dy == r)) {
                        const int x0 = max(cx - r, 0), x1 = min(cx + r, G_ - 1);
                        scan_glb(sp, csg[rb + x0], csg[rb + x1 + 1], l, px, py, pz, t);
                    } else {
                        const int xm = cx - r, xp = cx + r;
                        if (xm >= 0) scan_glb(sp, csg[rb + xm], csg[rb + xm + 1], l, px, py, pz, t);
                        if (xp < G_) scan_glb(sp, csg[rb + xp], csg[rb + xp + 1], l, px, py, pz, t);
                    }
                }
            }
        }
        // Valid upper bound: union 8th <= min over the 4 lanes' per-lane 8th.
        float e = t[KNN_ - 1];
        e = fminf(e, __shfl_xor(e, 1));
        e = fminf(e, __shfl_xor(e, 2));
        m = fminf(m, e);
    }

    // Final exact top-8 of the 4 disjoint lane lists.
    merge_pair(t, 1); merge_pair(t, 2);

    float tsum = 0.0f;
    if (l == 0) {
#pragma unroll
        for (int k = 0; k < KNN_; k++) {
            const float dm = fmaxf(t[k], 1e-12f);   // self: d2=0 -> dn=1e-6
            const float dn = sqrtf(dm);
            tsum += (RADIUS_ - dn) * __expf(-dm * INV_H2_);
        }
    }
#pragma unroll
    for (int off = 1; off < 64; off <<= 1) tsum += __shfl_xor(tsum, off);
    if ((tid & 63) == 0) bsum[tid >> 6] = tsum;
    __syncthreads();
    if (tid == 0) {
        float s = 0.0f;
#pragma unroll
        for (int w = 0; w < 8; w++) s += bsum[w];
        atomicAdd(out, s * SCALE_);
    }
}

extern "C" void kernel_launch(void* const* d_in, const int* in_sizes, int n_in,
                              void* d_out, int out_size, void* d_ws, size_t ws_size,
                              hipStream_t stream) {
    const float* pts = (const float*)d_in[0];
    float*       out = (float*)d_out;

    char* ws = (char*)d_ws;
    float4* sorted4   = (float4*)(ws);                            // 524288 B
    int*    counts    = (int*)(ws + 524288);                      //  27648 B
    int*    cellStart = (int*)(ws + 524288 + 27648);              //  27664 B
    int*    cursor    = (int*)(ws + 524288 + 27648 + 27664);      //  27648 B

    void* args[] = { (void*)&pts, (void*)&counts, (void*)&cellStart,
                     (void*)&cursor, (void*)&sorted4, (void*)&out };
    hipLaunchCooperativeKernel((void*)fused_kernel, dim3(BLOCKS_), dim3(THREADS_),
                               args, 0, stream);
}

// Round 6
// 121.076 us; speedup vs baseline: 2.8746x; 2.8746x over previous
//
#include <hip/hip_runtime.h>

// RepulsionLoss: points [B=4, N=8192, 3] fp32 -> scalar.
// Round 14: revert R13's cooperative fusion (grid.sync cost ~60us each,
//   fused kernel 289us @ VALUBusy 2.3%). Back to the verified R12 5-dispatch
//   structure (107.6us anchor); change ONLY the query kernel:
//   (a) 512-thread blocks, 128 pts/block, 4 lanes/point -> 8 waves/CU =
//       2 waves/SIMD (R12 ran 1/SIMD, Occ 4.76%: nothing hid LDS latency).
//       __launch_bounds__(512,2) so VGPRs stay <=256 (R13's 52-VGPR alloc
//       suggested spill pressure at default bounds).
//   (b) ring-2 LDS walk round-robins WHOLE ROWS across the 4 lanes: per-lane
//       dependent chain 98 rows -> ~24 rows (per-row bound-read latency was
//       the cost, not candidate count); rows independent -> can overlap.
//   Rings 0+1 stay candidate-split 4-way (~3.5 trips/span).

#define B_    4
#define N_    8192
#define KNN_  8
#define G_    12
#define C_    (G_ * G_ * G_)   // 1728
#define CS_   (C_ + 1)
#define PLANE_ (G_ * G_)       // 144
#define SLAB_CAP 4608          // float4 slots: 6 planes avg 4096, 11-sigma cap
#define CS_CAP   (6 * PLANE_ + 1)  // 865
#define QTHREADS_ 512

constexpr float GF_     = (float)G_;
constexpr float CELL_   = 1.0f / GF_;
constexpr float RADIUS_ = 0.07f;
constexpr float INV_H2_ = 1.0f / (0.03f * 0.03f);
constexpr float SCALE_  = 0.1f / (float)(B_ * N_ * KNN_);   // ALPHA / (B*N*K)

__device__ __forceinline__ int cell_coord(float x) {
    int c = (int)(x * GF_);
    return min(max(c, 0), G_ - 1);
}

__device__ __forceinline__ void insert8(float (&t)[KNN_], float v) {
#pragma unroll
    for (int k = 0; k < KNN_; k++) {
        const float lo = fminf(t[k], v);
        v = fmaxf(t[k], v);
        t[k] = lo;
    }
}

// One bitonic merge stage across lane pairs (xor dist): both lanes end with
// the sorted min-8 of the union of their two sorted lists. Valid for disjoint
// candidate multisets.
__device__ __forceinline__ void merge_pair(float (&t)[KNN_], const int dist) {
    float u[KNN_];
#pragma unroll
    for (int i2 = 0; i2 < KNN_; i2++)
        u[i2] = fminf(t[i2], __shfl_xor(t[KNN_ - 1 - i2], dist));
#pragma unroll
    for (int d = 4; d >= 1; d >>= 1) {
#pragma unroll
        for (int i2 = 0; i2 < KNN_; i2++) {
            if ((i2 & d) == 0) {
                const float a = u[i2], e = u[i2 + d];
                u[i2] = fminf(a, e); u[i2 + d] = fmaxf(a, e);
            }
        }
    }
#pragma unroll
    for (int i2 = 0; i2 < KNN_; i2++) t[i2] = u[i2];
}

// Candidate-split span scan from the LDS slab (slab-local indices), 4-way.
__device__ __forceinline__ void scan_lds(const float4 (&sl)[SLAB_CAP],
                                         int j0, int j1, int l,
                                         float px, float py, float pz,
                                         float (&t)[KNN_]) {
    for (int j = j0 + l; j < j1; j += 4) {
        const float4 Q = sl[j];
        const float dx = px - Q.x, dy = py - Q.y, dz = pz - Q.z;
        const float d2 = dx * dx + dy * dy + dz * dz;
        if (d2 < t[KNN_ - 1]) insert8(t, d2);
    }
}

// Whole-row scan from the LDS slab: one lane owns the full row.
__device__ __forceinline__ void scan_lds_row(const float4 (&sl)[SLAB_CAP],
                                             int j0, int j1,
                                             float px, float py, float pz,
                                             float (&t)[KNN_]) {
#pragma unroll 2
    for (int j = j0; j < j1; ++j) {
        const float4 Q = sl[j];
        const float dx = px - Q.x, dy = py - Q.y, dz = pz - Q.z;
        const float d2 = dx * dx + dy * dy + dz * dz;
        if (d2 < t[KNN_ - 1]) insert8(t, d2);
    }
}

// Span scan from global memory (ring >=3 only, essentially never).
__device__ __forceinline__ void scan_glb(const float4* __restrict__ sp,
                                         int j0, int j1, int l,
                                         float px, float py, float pz,
                                         float (&t)[KNN_]) {
    for (int j = j0 + l; j < j1; j += 4) {
        const float4 Q = sp[j];
        const float dx = px - Q.x, dy = py - Q.y, dz = pz - Q.z;
        const float d2 = dx * dx + dy * dy + dz * dz;
        if (d2 < t[KNN_ - 1]) insert8(t, d2);
    }
}

__global__ __launch_bounds__(256) void count_kernel(const float* __restrict__ pts,
                                                    int* __restrict__ counts,
                                                    float* __restrict__ out) {
    const int g = blockIdx.x * 256 + threadIdx.x;   // 0..B*N-1
    if (g == 0) out[0] = 0.0f;                      // out re-poisoned each replay
    const int b = g >> 13;
    const float x = pts[g * 3 + 0], y = pts[g * 3 + 1], z = pts[g * 3 + 2];
    const int id = (cell_coord(z) * G_ + cell_coord(y)) * G_ + cell_coord(x);
    atomicAdd(&counts[b * C_ + id], 1);
}

// 4 blocks (one per batch): 7 cells/thread, shfl wave-scan + 4 wave partials.
__global__ __launch_bounds__(256) void scan_kernel(const int* __restrict__ counts,
                                                   int* __restrict__ cellStart,
                                                   int* __restrict__ cursor) {
    __shared__ int wsum[4];
    const int b = blockIdx.x, t = threadIdx.x;
    const int lane = t & 63, w = t >> 6;
    const int* cnt = counts + b * C_;
    int vals[7], tot = 0;
    const int c0 = t * 7;                            // 256*7 = 1792 >= 1728
#pragma unroll
    for (int k = 0; k < 7; k++) {
        const int c = c0 + k;
        const int v = (c < C_) ? cnt[c] : 0;
        vals[k] = v; tot += v;
    }
    int incl = tot;
#pragma unroll
    for (int off = 1; off < 64; off <<= 1) {
        const int v = __shfl_up(incl, off, 64);
        if (lane >= off) incl += v;
    }
    if (lane == 63) wsum[w] = incl;
    __syncthreads();
    int woff = 0;
    for (int ww = 0; ww < w; ww++) woff += wsum[ww];
    int run = woff + incl - tot;                     // exclusive base
#pragma unroll
    for (int k = 0; k < 7; k++) {
        const int c = c0 + k;
        if (c < C_) {
            cellStart[b * CS_ + c] = run;
            cursor[b * C_ + c]     = run;
            run += vals[k];
        }
    }
    if (t == 255) cellStart[b * CS_ + C_] = N_;
}

__global__ __launch_bounds__(256) void scatter_kernel(const float* __restrict__ pts,
                                                      int* __restrict__ cursor,
                                                      float4* __restrict__ sorted4) {
    const int g = blockIdx.x * 256 + threadIdx.x;
    const int b = g >> 13;
    const float x = pts[g * 3 + 0], y = pts[g * 3 + 1], z = pts[g * 3 + 2];
    const int id = (cell_coord(z) * G_ + cell_coord(y)) * G_ + cell_coord(x);
    const int pos = atomicAdd(&cursor[b * C_ + id], 1);
    sorted4[(size_t)b * N_ + pos] = make_float4(x, y, z, 0.0f);
}

// 256 blocks x 512 threads: 128 sorted points/block, 4 lanes/point.
// 8 waves/CU = 2 waves/SIMD; launch_bounds(512,2) -> VGPR cap 256.
__global__ __launch_bounds__(QTHREADS_, 2) void query_kernel(
    const float4* __restrict__ sorted4,
    const int* __restrict__ cellStart,
    float* __restrict__ out)
{
    __shared__ float4 slab[SLAB_CAP];
    __shared__ int    scs[CS_CAP];
    __shared__ float  bsum[8];

    const int tid  = threadIdx.x;
    const int b    = blockIdx.x >> 6;                  // 64 blocks/batch
    const int base = (blockIdx.x & 63) << 7;           // first point of block
    const int i    = base + (tid >> 2);                // this thread's point
    const int l    = tid & 3;                          // lane within point

    const int*    csg = cellStart + b * CS_;
    const float4* sp  = sorted4 + (size_t)b * N_;

    // Slab: block's points are cell-sorted; all ring<=2 reach lies in
    // z-planes [zf-2, zl+2] (<=6 planes; SLAB_CAP is ~11 sigma).
    const int zf  = cell_coord(sp[base].z);
    const int zl  = cell_coord(sp[base + 127].z);
    const int zlo = max(zf - 2, 0), zhi = min(zl + 2, G_ - 1);
    const int cs0 = zlo * PLANE_;
    const int cs1 = (zhi + 1) * PLANE_;                // <= C_
    const int start = csg[cs0];
    const int cnt   = csg[cs1] - start;
    const int csn   = cs1 - cs0 + 1;
    for (int k = tid; k < csn; k += QTHREADS_) scs[k]  = csg[cs0 + k];
    for (int k = tid; k < cnt; k += QTHREADS_) slab[k] = sp[start + k];
    __syncthreads();

    const float4 P = slab[i - start];
    const float px = P.x, py = P.y, pz = P.z;
    const int cx = cell_coord(px), cy = cell_coord(py), cz = cell_coord(pz);

    // Rings 0+1: 9 raster-contiguous x-rows, bounds from LDS cellStart slice.
    const int xa = max(cx - 1, 0), xb = min(cx + 1, G_ - 1);
    int j0[9], j1[9];
#pragma unroll
    for (int n = 0; n < 9; n++) {
        const int dz = n / 3 - 1, dy = n % 3 - 1;
        const int z = cz + dz, y = cy + dy;
        if ((unsigned)z < G_ && (unsigned)y < G_) {
            const int rb = (z * G_ + y) * G_ - cs0;
            j0[n] = scs[rb + xa] - start;
            j1[n] = scs[rb + xb + 1] - start;
        } else { j0[n] = 0; j1[n] = 0; }
    }

    float t[KNN_];
#pragma unroll
    for (int k = 0; k < KNN_; k++) t[k] = 1e30f;

#pragma unroll
    for (int n = 0; n < 9; n++)
        scan_lds(slab, j0[n], j1[n], l, px, py, pz, t);

    // True merged 8th-NN bound over the 4 lanes via temp copy.
    float m;
    {
        float tmp[KNN_];
#pragma unroll
        for (int k = 0; k < KNN_; k++) tmp[k] = t[k];
        merge_pair(tmp, 1); merge_pair(tmp, 2);
        m = tmp[KNN_ - 1];
    }

    // Exact fallback: ring r while ((r-1)*g)^2 < m. r==2 reads LDS (staged)
    // with WHOLE ROWS round-robined across the 4 lanes (per-lane dependent
    // chain 98 -> ~24 rows); r>=3 (8th-NN > 2 cells, essentially never)
    // reads global. Lane lists stay disjoint (each row owned by one lane).
    for (int r = 2; r < G_; r++) {
        const float dmin = (float)(r - 1) * CELL_;
        if (dmin * dmin >= m) break;
        if (r == 2) {
            int nrow = 0;
            for (int dz = -2; dz <= 2; ++dz) {
                const int z = cz + dz; if ((unsigned)z >= G_) continue;
                const bool zface = (dz == -2) | (dz == 2);
                for (int dy = -2; dy <= 2; ++dy) {
                    const int y = cy + dy; if ((unsigned)y >= G_) continue;
                    const int rb = (z * G_ + y) * G_ - cs0;
                    if (zface | (dy == -2) | (dy == 2)) {
                        if ((nrow++ & 3) == l) {
                            const int x0 = max(cx - 2, 0), x1 = min(cx + 2, G_ - 1);
                            scan_lds_row(slab, scs[rb + x0] - start,
                                         scs[rb + x1 + 1] - start, px, py, pz, t);
                        }
                    } else {
                        const int xm = cx - 2, xp = cx + 2;
                        if (xm >= 0) {
                            if ((nrow++ & 3) == l)
                                scan_lds_row(slab, scs[rb + xm] - start,
                                             scs[rb + xm + 1] - start, px, py, pz, t);
                        }
                        if (xp < G_) {
                            if ((nrow++ & 3) == l)
                                scan_lds_row(slab, scs[rb + xp] - start,
                                             scs[rb + xp + 1] - start, px, py, pz, t);
                        }
                    }
                }
            }
        } else {
            for (int dz = -r; dz <= r; ++dz) {
                const int z = cz + dz; if ((unsigned)z >= G_) continue;
                const bool zface = (dz == -r) | (dz == r);
                for (int dy = -r; dy <= r; ++dy) {
                    const int y = cy + dy; if ((unsigned)y >= G_) continue;
                    const int rb = (z * G_ + y) * G_;
                    if (zface | (dy == -r) | (dy == r)) {
                        const int x0 = max(cx - r, 0), x1 = min(cx + r, G_ - 1);
                        scan_glb(sp, csg[rb + x0], csg[rb + x1 + 1], l, px, py, pz, t);
                    } else {
                        const int xm = cx - r, xp = cx + r;
                        if (xm >= 0) scan_glb(sp, csg[rb + xm], csg[rb + xm + 1], l, px, py, pz, t);
                        if (xp < G_) scan_glb(sp, csg[rb + xp], csg[rb + xp + 1], l, px, py, pz, t);
                    }
                }
            }
        }
        // Valid upper bound: union 8th <= min over the 4 lanes' per-lane 8th.
        float e = t[KNN_ - 1];
        e = fminf(e, __shfl_xor(e, 1));
        e = fminf(e, __shfl_xor(e, 2));
        m = fminf(m, e);
    }

    // Final exact top-8 of the 4 disjoint lane lists.
    merge_pair(t, 1); merge_pair(t, 2);

    float tsum = 0.0f;
    if (l == 0) {
#pragma unroll
        for (int k = 0; k < KNN_; k++) {
            const float dm = fmaxf(t[k], 1e-12f);   // self: d2=0 -> dn=1e-6
            const float dn = sqrtf(dm);
            tsum += (RADIUS_ - dn) * __expf(-dm * INV_H2_);
        }
    }
#pragma unroll
    for (int off = 1; off < 64; off <<= 1) tsum += __shfl_xor(tsum, off);
    if ((tid & 63) == 0) bsum[tid >> 6] = tsum;
    __syncthreads();
    if (tid == 0) {
        float s = 0.0f;
#pragma unroll
        for (int w = 0; w < 8; w++) s += bsum[w];
        atomicAdd(out, s * SCALE_);
    }
}

extern "C" void kernel_launch(void* const* d_in, const int* in_sizes, int n_in,
                              void* d_out, int out_size, void* d_ws, size_t ws_size,
                              hipStream_t stream) {
    const float* pts = (const float*)d_in[0];
    float*       out = (float*)d_out;

    char* ws = (char*)d_ws;
    float4* sorted4   = (float4*)(ws);                            // 524288 B
    int*    counts    = (int*)(ws + 524288);                      //  27648 B
    int*    cellStart = (int*)(ws + 524288 + 27648);              //  27664 B
    int*    cursor    = (int*)(ws + 524288 + 27648 + 27664);      //  27648 B

    hipMemsetAsync(counts, 0, B_ * C_ * sizeof(int), stream);
    count_kernel  <<<B_ * N_ / 256, 256, 0, stream>>>(pts, counts, out);
    scan_kernel   <<<B_,            256, 0, stream>>>(counts, cellStart, cursor);
    scatter_kernel<<<B_ * N_ / 256, 256, 0, stream>>>(pts, cursor, sorted4);
    query_kernel  <<<B_ * N_ / 128, QTHREADS_, 0, stream>>>(sorted4, cellStart, out);
}

// Round 7
// 76.193 us; speedup vs baseline: 4.5679x; 1.5891x over previous
//
#include <hip/hip_runtime.h>

// RepulsionLoss: points [B=4, N=8192, 3] fp32 -> scalar.
// Round 15:
//   R14 post-mortem: divergent row round-robin SERIALIZES rows (each row's
//   scan is a different program point; 1/4 lanes active each) -> per-wave
//   ring-2 trips 686 -> 1372; 63.7/48 = 1372/686 x 0.67 overlap. Model:
//   query time = per-wave serialized LDS trips / wave-overlap. Splits must
//   be candidate-stride IN THE SAME loop instance.
//   Changes:
//   (1) Build fused to ONE kernel: 4 blocks (1/batch) x 1024 thr, LDS
//       histogram + shfl scan + LDS-cursor scatter, points stashed in regs.
//       Replaces memset+count+scan+scatter (~50us dispatches+gaps) with ~10us.
//   (2) Query 512 thr, 4 lanes/pt, stride-4 candidate split everywhere
//       (no divergent ownership) -> ring-2 per-wave trips 686->343, 2 w/SIMD.
//   (3) Ring-2 row trimming: rem = m - az^2 - ay^2 (exact point-to-slab
//       dists); skip row if rem<=0 else clip x-range to [px-sqrt(rem),
//       px+sqrt(rem)]. Skipped candidates have d^2 >= m -> exact.

#define B_    4
#define N_    8192
#define KNN_  8
#define G_    12
#define C_    (G_ * G_ * G_)   // 1728
#define CS_   (C_ + 1)
#define PLANE_ (G_ * G_)       // 144
#define SLAB_CAP 4608          // float4 slots: 6 planes avg 4096, 11-sigma cap
#define CS_CAP   (6 * PLANE_ + 1)  // 865
#define QTHREADS_ 512
#define BTHREADS_ 1024

constexpr float GF_     = (float)G_;
constexpr float CELL_   = 1.0f / GF_;
constexpr float RADIUS_ = 0.07f;
constexpr float INV_H2_ = 1.0f / (0.03f * 0.03f);
constexpr float SCALE_  = 0.1f / (float)(B_ * N_ * KNN_);   // ALPHA / (B*N*K)

__device__ __forceinline__ int cell_coord(float x) {
    int c = (int)(x * GF_);
    return min(max(c, 0), G_ - 1);
}

__device__ __forceinline__ void insert8(float (&t)[KNN_], float v) {
#pragma unroll
    for (int k = 0; k < KNN_; k++) {
        const float lo = fminf(t[k], v);
        v = fmaxf(t[k], v);
        t[k] = lo;
    }
}

// One bitonic merge stage across lane pairs (xor dist): both lanes end with
// the sorted min-8 of the union of their two sorted lists. Valid for disjoint
// candidate multisets.
__device__ __forceinline__ void merge_pair(float (&t)[KNN_], const int dist) {
    float u[KNN_];
#pragma unroll
    for (int i2 = 0; i2 < KNN_; i2++)
        u[i2] = fminf(t[i2], __shfl_xor(t[KNN_ - 1 - i2], dist));
#pragma unroll
    for (int d = 4; d >= 1; d >>= 1) {
#pragma unroll
        for (int i2 = 0; i2 < KNN_; i2++) {
            if ((i2 & d) == 0) {
                const float a = u[i2], e = u[i2 + d];
                u[i2] = fminf(a, e); u[i2 + d] = fmaxf(a, e);
            }
        }
    }
#pragma unroll
    for (int i2 = 0; i2 < KNN_; i2++) t[i2] = u[i2];
}

// Candidate-split span scan from the LDS slab (slab-local indices), 4-way.
// All lanes in the SAME loop instance -> true SIMT parallel split.
__device__ __forceinline__ void scan_lds(const float4 (&sl)[SLAB_CAP],
                                         int j0, int j1, int l,
                                         float px, float py, float pz,
                                         float (&t)[KNN_]) {
    for (int j = j0 + l; j < j1; j += 4) {
        const float4 Q = sl[j];
        const float dx = px - Q.x, dy = py - Q.y, dz = pz - Q.z;
        const float d2 = dx * dx + dy * dy + dz * dz;
        if (d2 < t[KNN_ - 1]) insert8(t, d2);
    }
}

// Span scan from global memory (ring >=3 only, essentially never).
__device__ __forceinline__ void scan_glb(const float4* __restrict__ sp,
                                         int j0, int j1, int l,
                                         float px, float py, float pz,
                                         float (&t)[KNN_]) {
    for (int j = j0 + l; j < j1; j += 4) {
        const float4 Q = sp[j];
        const float dx = px - Q.x, dy = py - Q.y, dz = pz - Q.z;
        const float d2 = dx * dx + dy * dy + dz * dz;
        if (d2 < t[KNN_ - 1]) insert8(t, d2);
    }
}

// ---- fused build: 4 blocks (one per batch) x 1024 threads ----
// LDS histogram -> 256-thread shfl scan (R8-proven pattern) -> LDS-cursor
// scatter. Points stashed in registers between phases (static indexing).
__global__ __launch_bounds__(BTHREADS_) void build_kernel(
    const float* __restrict__ pts,
    int* __restrict__ cellStart,
    float4* __restrict__ sorted4,
    float* __restrict__ out)
{
    __shared__ int lcnt[C_];
    __shared__ int lcur[C_];
    __shared__ int wsum[4];

    const int b = blockIdx.x, tid = threadIdx.x;
    if (b == 0 && tid == 0) out[0] = 0.0f;          // out re-poisoned each replay
    for (int k = tid; k < C_; k += BTHREADS_) lcnt[k] = 0;
    __syncthreads();

    float fx[8], fy[8], fz[8]; int id[8];
#pragma unroll
    for (int k = 0; k < 8; k++) {
        const int g = b * N_ + k * BTHREADS_ + tid;
        fx[k] = pts[g * 3 + 0]; fy[k] = pts[g * 3 + 1]; fz[k] = pts[g * 3 + 2];
        id[k] = (cell_coord(fz[k]) * G_ + cell_coord(fy[k])) * G_ + cell_coord(fx[k]);
        atomicAdd(&lcnt[id[k]], 1);
    }
    __syncthreads();

    // scan: tid<256, 7 cells each (256*7=1792>=1728); barriers outside guards.
    const int lane = tid & 63, w = tid >> 6;
    int vals[7], tot = 0, incl = 0;
    const int c0 = tid * 7;
    if (tid < 256) {
#pragma unroll
        for (int k = 0; k < 7; k++) {
            const int c = c0 + k;
            const int v = (c < C_) ? lcnt[c] : 0;
            vals[k] = v; tot += v;
        }
        incl = tot;
#pragma unroll
        for (int off = 1; off < 64; off <<= 1) {
            const int v = __shfl_up(incl, off, 64);
            if (lane >= off) incl += v;
        }
        if (tid < 256 && lane == 63) wsum[w] = incl;
    }
    __syncthreads();
    if (tid < 256) {
        int woff = 0;
        for (int ww = 0; ww < w; ww++) woff += wsum[ww];
        int run = woff + incl - tot;                 // exclusive base
#pragma unroll
        for (int k = 0; k < 7; k++) {
            const int c = c0 + k;
            if (c < C_) {
                cellStart[b * CS_ + c] = run;
                lcur[c] = run;
                run += vals[k];
            }
        }
        if (tid == 255) cellStart[b * CS_ + C_] = N_;
    }
    __syncthreads();

    // scatter from stashed registers via LDS cursors
#pragma unroll
    for (int k = 0; k < 8; k++) {
        const int pos = atomicAdd(&lcur[id[k]], 1);
        sorted4[(size_t)b * N_ + pos] = make_float4(fx[k], fy[k], fz[k], 0.0f);
    }
}

// ---- query: 256 blocks x 512 threads, 128 sorted points/block, 4 lanes/pt ----
__global__ __launch_bounds__(QTHREADS_) void query_kernel(
    const float4* __restrict__ sorted4,
    const int* __restrict__ cellStart,
    float* __restrict__ out)
{
    __shared__ float4 slab[SLAB_CAP];
    __shared__ int    scs[CS_CAP];
    __shared__ float  bsum[8];

    const int tid  = threadIdx.x;
    const int b    = blockIdx.x >> 6;                  // 64 blocks/batch
    const int base = (blockIdx.x & 63) << 7;           // first point of block
    const int i    = base + (tid >> 2);                // this thread's point
    const int l    = tid & 3;                          // lane within point

    const int*    csg = cellStart + b * CS_;
    const float4* sp  = sorted4 + (size_t)b * N_;

    // Slab: block's points are cell-sorted; all ring<=2 reach lies in
    // z-planes [zf-2, zl+2] (<=6 planes; SLAB_CAP is ~11 sigma).
    const int zf  = cell_coord(sp[base].z);
    const int zl  = cell_coord(sp[base + 127].z);
    const int zlo = max(zf - 2, 0), zhi = min(zl + 2, G_ - 1);
    const int cs0 = zlo * PLANE_;
    const int cs1 = (zhi + 1) * PLANE_;                // <= C_
    const int start = csg[cs0];
    const int cnt   = csg[cs1] - start;
    const int csn   = cs1 - cs0 + 1;
    for (int k = tid; k < csn; k += QTHREADS_) scs[k]  = csg[cs0 + k];
    for (int k = tid; k < cnt; k += QTHREADS_) slab[k] = sp[start + k];
    __syncthreads();

    const float4 P = slab[i - start];
    const float px = P.x, py = P.y, pz = P.z;
    const int cx = cell_coord(px), cy = cell_coord(py), cz = cell_coord(pz);

    // Rings 0+1: 9 raster-contiguous x-rows, bounds from LDS cellStart slice.
    const int xa = max(cx - 1, 0), xb = min(cx + 1, G_ - 1);
    int j0[9], j1[9];
#pragma unroll
    for (int n = 0; n < 9; n++) {
        const int dz = n / 3 - 1, dy = n % 3 - 1;
        const int z = cz + dz, y = cy + dy;
        if ((unsigned)z < G_ && (unsigned)y < G_) {
            const int rb = (z * G_ + y) * G_ - cs0;
            j0[n] = scs[rb + xa] - start;
            j1[n] = scs[rb + xb + 1] - start;
        } else { j0[n] = 0; j1[n] = 0; }
    }

    float t[KNN_];
#pragma unroll
    for (int k = 0; k < KNN_; k++) t[k] = 1e30f;

#pragma unroll
    for (int n = 0; n < 9; n++)
        scan_lds(slab, j0[n], j1[n], l, px, py, pz, t);

    // True merged 8th-NN bound over the 4 lanes via temp copy.
    float m;
    {
        float tmp[KNN_];
#pragma unroll
        for (int k = 0; k < KNN_; k++) tmp[k] = t[k];
        merge_pair(tmp, 1); merge_pair(tmp, 2);
        m = tmp[KNN_ - 1];
    }

    // Ring 2 (LDS, trimmed): for each row (z,y), az/ay = exact min distance
    // from the point to that cell slab; skip row if az^2+ay^2 >= m, else clip
    // the x-range to cells intersecting [px-w, px+w], w = sqrt(m-az^2-ay^2).
    // Any skipped candidate has d^2 >= m -> exact. Inner rows (|dz|<=1 and
    // |dy|<=1) contribute only their x = cx+-2 ring cells.
    if (CELL_ * CELL_ < m) {
        for (int dz = -2; dz <= 2; ++dz) {
            const int z = cz + dz; if ((unsigned)z >= G_) continue;
            const float azv = fmaxf(fmaxf(z * CELL_ - pz, pz - (z + 1) * CELL_), 0.0f);
            for (int dy = -2; dy <= 2; ++dy) {
                const int y = cy + dy; if ((unsigned)y >= G_) continue;
                const float ayv = fmaxf(fmaxf(y * CELL_ - py, py - (y + 1) * CELL_), 0.0f);
                const float rem = m - azv * azv - ayv * ayv;
                if (rem <= 0.0f) continue;
                const float wr = sqrtf(rem);
                const int xl = max(cell_coord(px - wr), cx - 2);
                const int xr = min(cell_coord(px + wr), cx + 2);
                const int rb = (z * G_ + y) * G_ - cs0;
                const bool innerzy = (dz >= -1) & (dz <= 1) & (dy >= -1) & (dy <= 1);
                if (!innerzy) {
                    if (xl <= xr)
                        scan_lds(slab, scs[rb + xl] - start, scs[rb + xr + 1] - start,
                                 l, px, py, pz, t);
                } else {
                    if (xl <= cx - 2)   // implies cx-2 >= 0 (xl >= 0)
                        scan_lds(slab, scs[rb + cx - 2] - start, scs[rb + cx - 1] - start,
                                 l, px, py, pz, t);
                    if (xr >= cx + 2)   // implies cx+2 <= 11 (xr <= 11)
                        scan_lds(slab, scs[rb + cx + 2] - start, scs[rb + cx + 3] - start,
                                 l, px, py, pz, t);
                }
            }
        }
        float e = t[KNN_ - 1];
        e = fminf(e, __shfl_xor(e, 1));
        e = fminf(e, __shfl_xor(e, 2));
        m = fminf(m, e);
    }

    // Ring >=3 (global, essentially never): exact fallback.
    for (int r = 3; r < G_; r++) {
        const float dmin = (float)(r - 1) * CELL_;
        if (dmin * dmin >= m) break;
        for (int dz = -r; dz <= r; ++dz) {
            const int z = cz + dz; if ((unsigned)z >= G_) continue;
            const bool zface = (dz == -r) | (dz == r);
            for (int dy = -r; dy <= r; ++dy) {
                const int y = cy + dy; if ((unsigned)y >= G_) continue;
                const int rb = (z * G_ + y) * G_;
                if (zface | (dy == -r) | (dy == r)) {
                    const int x0 = max(cx - r, 0), x1 = min(cx + r, G_ - 1);
                    scan_glb(sp, csg[rb + x0], csg[rb + x1 + 1], l, px, py, pz, t);
                } else {
                    const int xm = cx - r, xp = cx + r;
                    if (xm >= 0) scan_glb(sp, csg[rb + xm], csg[rb + xm + 1], l, px, py, pz, t);
                    if (xp < G_) scan_glb(sp, csg[rb + xp], csg[rb + xp + 1], l, px, py, pz, t);
                }
            }
        }
        float e = t[KNN_ - 1];
        e = fminf(e, __shfl_xor(e, 1));
        e = fminf(e, __shfl_xor(e, 2));
        m = fminf(m, e);
    }

    // Final exact top-8 of the 4 disjoint lane lists.
    merge_pair(t, 1); merge_pair(t, 2);

    float tsum = 0.0f;
    if (l == 0) {
#pragma unroll
        for (int k = 0; k < KNN_; k++) {
            const float dm = fmaxf(t[k], 1e-12f);   // self: d2=0 -> dn=1e-6
            const float dn = sqrtf(dm);
            tsum += (RADIUS_ - dn) * __expf(-dm * INV_H2_);
        }
    }
#pragma unroll
    for (int off = 1; off < 64; off <<= 1) tsum += __shfl_xor(tsum, off);
    if ((tid & 63) == 0) bsum[tid >> 6] = tsum;
    __syncthreads();
    if (tid == 0) {
        float s = 0.0f;
#pragma unroll
        for (int w = 0; w < 8; w++) s += bsum[w];
        atomicAdd(out, s * SCALE_);
    }
}

extern "C" void kernel_launch(void* const* d_in, const int* in_sizes, int n_in,
                              void* d_out, int out_size, void* d_ws, size_t ws_size,
                              hipStream_t stream) {
    const float* pts = (const float*)d_in[0];
    float*       out = (float*)d_out;

    char* ws = (char*)d_ws;
    float4* sorted4   = (float4*)(ws);                            // 524288 B
    int*    cellStart = (int*)(ws + 524288);                      //  27664 B

    build_kernel<<<B_,            BTHREADS_, 0, stream>>>(pts, cellStart, sorted4, out);
    query_kernel<<<B_ * N_ / 128, QTHREADS_, 0, stream>>>(sorted4, cellStart, out);
}